// Round 2
// baseline (1433.883 us; speedup 1.0000x reference)
//
#include <hip/hip_runtime.h>
#include <stdint.h>
#include <stddef.h>

typedef unsigned short u16;
typedef __attribute__((ext_vector_type(8))) short short8;    // 8 bf16 input frag (4 VGPRs)
typedef __attribute__((ext_vector_type(8))) unsigned short ushort8;
typedef __attribute__((ext_vector_type(4))) float f32x4;     // MFMA 16x16 accum

#define NTOK 64
#define DIM  512
#define QSTR 36      // q/k/O LDS row stride (u16): 72B rows spread banks (64B rows = 8-way conflict)
#define REGION 6912  // per-wave LDS u16: q[0:2304) k[2304:4608) | P[0:4608) | vt[4608:6912); O[0:2304)

__device__ __forceinline__ float bf2f(u16 u) {
  union { unsigned int i; float f; } x; x.i = ((unsigned int)u) << 16; return x.f;
}
__device__ __forceinline__ u16 f2bf(float f) {
  union { float f; unsigned int i; } x; x.f = f;
  unsigned int u = x.i;
  u += 0x7fffu + ((u >> 16) & 1u);   // RNE
  return (u16)(u >> 16);
}

__device__ __forceinline__ f32x4 shfl_xor4(f32x4 v, int m) {
  f32x4 r;
  #pragma unroll
  for (int e = 0; e < 4; ++e) r[e] = __shfl_xor(v[e], m, 64);
  return r;
}
__device__ __forceinline__ f32x4 max44(f32x4 a, f32x4 b) {
  f32x4 r;
  #pragma unroll
  for (int e = 0; e < 4; ++e) r[e] = fmaxf(a[e], b[e]);
  return r;
}

// ---------------- dtype detection ----------------
__global__ void detect_k(const u16* __restrict__ w_raw, int* __restrict__ flag) {
  if (threadIdx.x == 0 && blockIdx.x == 0) {
    int cnt = 0;
    for (int i = 0; i < 512; ++i) {
      float v = bf2f(w_raw[i]);
      if (!(v <= 0.5f && v >= -0.5f)) ++cnt;   // counts NaN too
    }
    flag[0] = (cnt > 16) ? 1 : 0;              // 1 = inputs are fp32
  }
}

// ---------------- prep kernels ----------------

// vectorized canonical bf16 copy: 8 elems/thread
__global__ void cvt8_k(const float* __restrict__ fsrc, const u16* __restrict__ usrc,
                       u16* __restrict__ dst, int n, const int* __restrict__ flag) {
  int i = (blockIdx.x * 256 + threadIdx.x) * 8;
  if (i >= n) return;
  if (flag[0]) {
    f32x4 a = *(const f32x4*)(fsrc + i);
    f32x4 b = *(const f32x4*)(fsrc + i + 4);
    ushort8 o;
    #pragma unroll
    for (int e = 0; e < 4; ++e) { o[e] = f2bf(a[e]); o[e + 4] = f2bf(b[e]); }
    *(ushort8*)(dst + i) = o;
  } else {
    *(ushort8*)(dst + i) = *(const ushort8*)(usrc + i);
  }
}

// dst[n*R+k] = (bf16) src[k*C+n]  (transpose to N x K)  -- one-time, tiny
__global__ void transpose_k(const float* __restrict__ fsrc, const u16* __restrict__ usrc,
                            u16* __restrict__ dst, int R, int C, const int* __restrict__ flag) {
  int idx = blockIdx.x * 256 + threadIdx.x;
  int n = idx / R, k = idx % R;
  if (flag[0]) dst[idx] = f2bf(fsrc[k * C + n]);
  else         dst[idx] = usrc[k * C + n];
}

// biasc[h][mi][ni][lane][r] = table[h, i1-i2+7, j1-j2+7] with
// n = mi*16 + (lane>>4)*4 + r (query row), m = ni*16 + (lane&15) (key col)
__global__ void bias_expand_k(const float* __restrict__ ftab, const u16* __restrict__ utab,
                              float* __restrict__ biasc, const int* __restrict__ flag) {
  int t = blockIdx.x * 256 + threadIdx.x;   // 65536 total
  int r    = t & 3;
  int lane = (t >> 2) & 63;
  int ni   = (t >> 8) & 3;
  int mi   = (t >> 10) & 3;
  int h    = t >> 12;
  int n = mi * 16 + (lane >> 4) * 4 + r;
  int m = ni * 16 + (lane & 15);
  int i1 = n >> 3, j1 = n & 7, i2 = m >> 3, j2 = m & 7;
  int off = h * 225 + (i1 - i2 + 7) * 15 + (j1 - j2 + 7);
  if (flag[0]) biasc[t] = ftab[off];
  else         biasc[t] = bf2f(utab[off]);
}

// ---------------- fully fused per-window kernel ----------------
// One block = one 64-token window. 8 waves; round r in {0,1}: wave w owns head h=r*8+w.
// Per round: per-wave qkv GEMM (64x96x512, A/B frags direct from global bf16, L1/L2-served)
//   -> q,k,v^T to private LDS -> attention (verified layout) -> O_h to LDS -> barrier
//   -> all waves accumulate proj rank-32 updates (out cols wave*64..+64) -> barrier.
// Epilogue: out = acc + b_proj, written straight to global (fp32 or bf16 per flag).
__global__ __launch_bounds__(512, 2) void fused_k(
    const u16* __restrict__ xbf,      // [win*64][512] chunk, canonical bf16
    const u16* __restrict__ wqkvT,    // [1536][512]
    const u16* __restrict__ bqc,      // [1536]
    const float* __restrict__ biasc,  // [16][4][4][64][4]
    const u16* __restrict__ wprojT,   // [512][512]
    const u16* __restrict__ bpc,      // [512]
    const int* __restrict__ flag,
    u16* __restrict__ outU, float* __restrict__ outF)
{
  __shared__ __attribute__((aligned(16))) u16 lds[8][REGION];   // 110,592 B

  const int lane = threadIdx.x & 63;
  const int wave = threadIdx.x >> 6;     // 0..7
  const int lr = lane & 15, quad = lane >> 4;
  const int blk = blockIdx.x;

  u16* ql = &lds[wave][0];
  u16* kl = &lds[wave][2304];
  u16* Pl = &lds[wave][0];       // P[64][72] overwrites q,k
  u16* vt = &lds[wave][4608];    // v^T[32][72]
  u16* Ol = &lds[wave][0];       // O_h[64][QSTR] overwrites P

  const u16* xw = xbf + (size_t)blk * NTOK * DIM;
  const float SCALE = 0.17677669529663687f;   // 32^-0.5
  const float L2E = 1.44269504088896f;
  const f32x4 zero4 = {0.f, 0.f, 0.f, 0.f};

  // persistent projection accumulators: out[64][wave*64 .. +64]
  f32x4 acc[4][4];
  #pragma unroll
  for (int mi = 0; mi < 4; ++mi)
    #pragma unroll
    for (int ni = 0; ni < 4; ++ni) acc[mi][ni] = zero4;

  for (int r = 0; r < 2; ++r) {
    const int h = r * 8 + wave;

    // ---- qkv GEMM for head h: M=64, N=96 (q|k|v x 2 tiles), K=512 ----
    f32x4 aq[4][2], ak[4][2], av[4][2];
    #pragma unroll
    for (int mi = 0; mi < 4; ++mi) {
      aq[mi][0] = zero4; aq[mi][1] = zero4;
      ak[mi][0] = zero4; ak[mi][1] = zero4;
      av[mi][0] = zero4; av[mi][1] = zero4;
    }
    const u16* ax = xw + (size_t)lr * DIM + quad * 8;
    const u16* wq = wqkvT + ((size_t)(h * 32 + lr)) * DIM + quad * 8;
    const u16* wk = wq + (size_t)512 * DIM;
    const u16* wv = wq + (size_t)1024 * DIM;
    #pragma unroll 4
    for (int ks = 0; ks < 16; ++ks) {
      const int ko = ks * 32;
      short8 af[4];
      #pragma unroll
      for (int mi = 0; mi < 4; ++mi)
        af[mi] = *(const short8*)(ax + mi * (16 * DIM) + ko);
      short8 b0 = *(const short8*)(wq + ko);
      short8 b1 = *(const short8*)(wq + 16 * DIM + ko);
      short8 b2 = *(const short8*)(wk + ko);
      short8 b3 = *(const short8*)(wk + 16 * DIM + ko);
      short8 b4 = *(const short8*)(wv + ko);
      short8 b5 = *(const short8*)(wv + 16 * DIM + ko);
      #pragma unroll
      for (int mi = 0; mi < 4; ++mi) {
        aq[mi][0] = __builtin_amdgcn_mfma_f32_16x16x32_bf16(af[mi], b0, aq[mi][0], 0, 0, 0);
        aq[mi][1] = __builtin_amdgcn_mfma_f32_16x16x32_bf16(af[mi], b1, aq[mi][1], 0, 0, 0);
        ak[mi][0] = __builtin_amdgcn_mfma_f32_16x16x32_bf16(af[mi], b2, ak[mi][0], 0, 0, 0);
        ak[mi][1] = __builtin_amdgcn_mfma_f32_16x16x32_bf16(af[mi], b3, ak[mi][1], 0, 0, 0);
        av[mi][0] = __builtin_amdgcn_mfma_f32_16x16x32_bf16(af[mi], b4, av[mi][0], 0, 0, 0);
        av[mi][1] = __builtin_amdgcn_mfma_f32_16x16x32_bf16(af[mi], b5, av[mi][1], 0, 0, 0);
      }
    }

    // bias + (q: scale) -> LDS. C-layout: tok = mi*16+quad*4+e, d = j*16+lr
    #pragma unroll
    for (int j = 0; j < 2; ++j) {
      float bq = bf2f(bqc[h * 32 + j * 16 + lr]);
      float bk = bf2f(bqc[512 + h * 32 + j * 16 + lr]);
      float bv = bf2f(bqc[1024 + h * 32 + j * 16 + lr]);
      #pragma unroll
      for (int mi = 0; mi < 4; ++mi)
        #pragma unroll
        for (int e = 0; e < 4; ++e) {
          int tok = mi * 16 + quad * 4 + e;
          int d = j * 16 + lr;
          ql[tok * QSTR + d] = f2bf((aq[mi][j][e] + bq) * SCALE);
          kl[tok * QSTR + d] = f2bf(ak[mi][j][e] + bk);
          vt[d * 72 + tok]   = f2bf(av[mi][j][e] + bv);
        }
    }
    // same-wave LDS RAW below: compiler inserts lgkmcnt waits

    // ---- S = q @ k^T (4x4 tiles, K=32) ----
    f32x4 s[4][4];
    {
      short8 afq[4], bfk[4];
      #pragma unroll
      for (int mi = 0; mi < 4; ++mi)
        afq[mi] = *(const short8*)&ql[(mi * 16 + lr) * QSTR + quad * 8];
      #pragma unroll
      for (int ni = 0; ni < 4; ++ni)
        bfk[ni] = *(const short8*)&kl[(ni * 16 + lr) * QSTR + quad * 8];
      #pragma unroll
      for (int mi = 0; mi < 4; ++mi)
        #pragma unroll
        for (int ni = 0; ni < 4; ++ni)
          s[mi][ni] = __builtin_amdgcn_mfma_f32_16x16x32_bf16(afq[mi], bfk[ni], zero4, 0, 0, 0);
    }

    // rel-pos bias (pre-expanded C-layout)
    #pragma unroll
    for (int mi = 0; mi < 4; ++mi)
      #pragma unroll
      for (int ni = 0; ni < 4; ++ni) {
        f32x4 bb = *(const f32x4*)&biasc[((((h * 4 + mi) * 4 + ni) * 64) + lane) * 4];
        s[mi][ni] = s[mi][ni] + bb;
      }

    // row max (masks 1..8 stay within the quad's 16-lane col group)
    f32x4 mx[4];
    #pragma unroll
    for (int mi = 0; mi < 4; ++mi) {
      mx[mi] = max44(max44(s[mi][0], s[mi][1]), max44(s[mi][2], s[mi][3]));
      #pragma unroll
      for (int m = 1; m <= 8; m <<= 1) mx[mi] = max44(mx[mi], shfl_xor4(mx[mi], m));
    }
    // p = exp(s - mx), row sum
    f32x4 sum[4];
    #pragma unroll
    for (int mi = 0; mi < 4; ++mi) {
      #pragma unroll
      for (int ni = 0; ni < 4; ++ni)
        #pragma unroll
        for (int e = 0; e < 4; ++e)
          s[mi][ni][e] = exp2f((s[mi][ni][e] - mx[mi][e]) * L2E);
      sum[mi] = s[mi][0] + s[mi][1] + s[mi][2] + s[mi][3];
      #pragma unroll
      for (int m = 1; m <= 8; m <<= 1) sum[mi] = sum[mi] + shfl_xor4(sum[mi], m);
    }

    // P (unnormalized) -> bf16 -> LDS, stride 72
    #pragma unroll
    for (int mi = 0; mi < 4; ++mi)
      #pragma unroll
      for (int ni = 0; ni < 4; ++ni)
        #pragma unroll
        for (int e = 0; e < 4; ++e) {
          int n = mi * 16 + quad * 4 + e;
          int col = ni * 16 + lr;
          Pl[n * 72 + col] = f2bf(s[mi][ni][e]);
        }

    // O = P @ v : M=64, N=32, K=64 (2 k-steps)
    f32x4 o[4][2];
    #pragma unroll
    for (int mi = 0; mi < 4; ++mi) { o[mi][0] = zero4; o[mi][1] = zero4; }
    #pragma unroll
    for (int ks = 0; ks < 2; ++ks) {
      short8 pf[4], vf[2];
      #pragma unroll
      for (int mi = 0; mi < 4; ++mi)
        pf[mi] = *(const short8*)&Pl[(mi * 16 + lr) * 72 + ks * 32 + quad * 8];
      #pragma unroll
      for (int ni = 0; ni < 2; ++ni)
        vf[ni] = *(const short8*)&vt[(ni * 16 + lr) * 72 + ks * 32 + quad * 8];
      #pragma unroll
      for (int mi = 0; mi < 4; ++mi)
        #pragma unroll
        for (int ni = 0; ni < 2; ++ni)
          o[mi][ni] = __builtin_amdgcn_mfma_f32_16x16x32_bf16(pf[mi], vf[ni], o[mi][ni], 0, 0, 0);
    }

    // normalize, O_h -> LDS as A-matrix [tok][d], stride QSTR
    f32x4 rs[4];
    #pragma unroll
    for (int mi = 0; mi < 4; ++mi)
      #pragma unroll
      for (int e = 0; e < 4; ++e) rs[mi][e] = __builtin_amdgcn_rcpf(sum[mi][e]);
    #pragma unroll
    for (int mi = 0; mi < 4; ++mi)
      #pragma unroll
      for (int ni = 0; ni < 2; ++ni)
        #pragma unroll
        for (int e = 0; e < 4; ++e) {
          int tok = mi * 16 + quad * 4 + e;
          int d = ni * 16 + lr;
          Ol[tok * QSTR + d] = f2bf(o[mi][ni][e] * rs[mi][e]);
        }

    __syncthreads();   // all O_h visible

    // ---- proj accumulate: out[:, wave*64..+64] += O_h2 @ Wproj[h2*32.., :] ----
    #pragma unroll
    for (int w2 = 0; w2 < 8; ++w2) {
      const u16* Ow = &lds[w2][0];
      const int h2 = r * 8 + w2;
      short8 afO[4], bfW[4];
      #pragma unroll
      for (int mi = 0; mi < 4; ++mi)
        afO[mi] = *(const short8*)&Ow[(mi * 16 + lr) * QSTR + quad * 8];
      #pragma unroll
      for (int ni = 0; ni < 4; ++ni)
        bfW[ni] = *(const short8*)&wprojT[((size_t)(wave * 64 + ni * 16 + lr)) * DIM + h2 * 32 + quad * 8];
      #pragma unroll
      for (int mi = 0; mi < 4; ++mi)
        #pragma unroll
        for (int ni = 0; ni < 4; ++ni)
          acc[mi][ni] = __builtin_amdgcn_mfma_f32_16x16x32_bf16(afO[mi], bfW[ni], acc[mi][ni], 0, 0, 0);
    }
    __syncthreads();   // O regions reusable next round
  }

  // ---- epilogue: out = acc + b_proj ----
  const int f32o = flag[0];
  #pragma unroll
  for (int ni = 0; ni < 4; ++ni) {
    int col = wave * 64 + ni * 16 + lr;
    float bv = bf2f(bpc[col]);
    #pragma unroll
    for (int mi = 0; mi < 4; ++mi) {
      size_t rowb = (size_t)(blk * NTOK + mi * 16 + quad * 4);
      #pragma unroll
      for (int e = 0; e < 4; ++e) {
        float val = acc[mi][ni][e] + bv;
        size_t ofs = (rowb + e) * (size_t)DIM + col;
        if (f32o) outF[ofs] = val;
        else      outU[ofs] = f2bf(val);
      }
    }
  }
}

// ---------------- launch ----------------

extern "C" void kernel_launch(void* const* d_in, const int* in_sizes, int n_in,
                              void* d_out, int out_size, void* d_ws, size_t ws_size,
                              hipStream_t stream)
{
  (void)in_sizes; (void)n_in; (void)out_size;

  const void* x      = d_in[0];   // [2048*64][512]
  const void* w_qkv  = d_in[1];   // [512][1536]
  const void* b_qkv  = d_in[2];   // [1536]
  const void* table  = d_in[3];   // [16][15][15]
  const void* w_proj = d_in[4];   // [512][512]
  const void* b_proj = d_in[5];   // [512]

  char* ws = (char*)d_ws;
  size_t off = 0;
  auto alloc = [&](size_t bytes) -> char* {
    char* p = ws + off; off += (bytes + 255) & ~(size_t)255; return p;
  };
  u16*   wqkvT  = (u16*)alloc(1572864);
  u16*   wprojT = (u16*)alloc(524288);
  float* biasc  = (float*)alloc(262144);
  u16*   bqc    = (u16*)alloc(3072);
  u16*   bpc    = (u16*)alloc(1024);
  int*   flag   = (int*)alloc(256);
  size_t fixed  = off;

  int win = 2048;                        // windows per chunk
  while (win > 2 && fixed + (size_t)win * 65536 > ws_size) win >>= 1;
  const int mc = win * 64;               // rows per chunk
  u16* xbfC = (u16*)alloc((size_t)mc * 512 * 2);

  detect_k<<<dim3(1), dim3(64), 0, stream>>>((const u16*)w_qkv, flag);
  transpose_k<<<dim3(3072), dim3(256), 0, stream>>>((const float*)w_qkv, (const u16*)w_qkv, wqkvT, 512, 1536, flag);
  transpose_k<<<dim3(1024), dim3(256), 0, stream>>>((const float*)w_proj, (const u16*)w_proj, wprojT, 512, 512, flag);
  bias_expand_k<<<dim3(256), dim3(256), 0, stream>>>((const float*)table, (const u16*)table, biasc, flag);
  cvt8_k<<<dim3(1), dim3(256), 0, stream>>>((const float*)b_qkv, (const u16*)b_qkv, bqc, 1536, flag);
  cvt8_k<<<dim3(1), dim3(256), 0, stream>>>((const float*)b_proj, (const u16*)b_proj, bpc, 512, flag);

  const int nchunk = 2048 / win;
  for (int c = 0; c < nchunk; ++c) {
    size_t base = (size_t)c * mc * 512;   // element offset into x / out

    cvt8_k<<<dim3((mc * 512) / 2048), dim3(256), 0, stream>>>(
        (const float*)x + base, (const u16*)x + base, xbfC, mc * 512, flag);

    fused_k<<<dim3(win), dim3(512), 0, stream>>>(
        xbfC, wqkvT, bqc, biasc, wprojT, bpc, flag,
        (u16*)d_out + base, (float*)d_out + base);
  }
}

// Round 4
// 1139.684 us; speedup vs baseline: 1.2581x; 1.2581x over previous
//
#include <hip/hip_runtime.h>
#include <stdint.h>
#include <stddef.h>

typedef unsigned short u16;
typedef __attribute__((ext_vector_type(8))) short short8;    // 8 bf16 input frag (4 VGPRs)
typedef __attribute__((ext_vector_type(8))) unsigned short ushort8;
typedef __attribute__((ext_vector_type(4))) unsigned short u16x4;
typedef __attribute__((ext_vector_type(4))) float f32x4;     // MFMA 16x16 accum

#define NTOK 64
#define DIM  512
#define QSTR 36      // q/k/O LDS row stride (u16): 72B rows spread banks
#define REGION 6912  // per-wave LDS u16: q[0:2304) k[2304:4608) | P[0:4608) | vt[4608:6912); O[0:2304)
#define XPAD 536     // cvtfrag LDS row stride (u16): 1072B = 16B-aligned, 2-way banks

__device__ __forceinline__ float bf2f(u16 u) {
  union { unsigned int i; float f; } x; x.i = ((unsigned int)u) << 16; return x.f;
}
__device__ __forceinline__ u16 f2bf(float f) {
  union { float f; unsigned int i; } x; x.f = f;
  unsigned int u = x.i;
  u += 0x7fffu + ((u >> 16) & 1u);   // RNE
  return (u16)(u >> 16);
}

__device__ __forceinline__ f32x4 shfl_xor4(f32x4 v, int m) {
  f32x4 r;
  #pragma unroll
  for (int e = 0; e < 4; ++e) r[e] = __shfl_xor(v[e], m, 64);
  return r;
}
__device__ __forceinline__ f32x4 max44(f32x4 a, f32x4 b) {
  f32x4 r;
  #pragma unroll
  for (int e = 0; e < 4; ++e) r[e] = fmaxf(a[e], b[e]);
  return r;
}

// ---------------- dtype detection ----------------
__global__ void detect_k(const u16* __restrict__ w_raw, int* __restrict__ flag) {
  if (threadIdx.x == 0 && blockIdx.x == 0) {
    int cnt = 0;
    for (int i = 0; i < 512; ++i) {
      float v = bf2f(w_raw[i]);
      if (!(v <= 0.5f && v >= -0.5f)) ++cnt;   // counts NaN too
    }
    flag[0] = (cnt > 16) ? 1 : 0;              // 1 = inputs are fp32
  }
}

// ---------------- prep kernels ----------------

// vectorized canonical bf16 copy (biases)
__global__ void cvt8_k(const float* __restrict__ fsrc, const u16* __restrict__ usrc,
                       u16* __restrict__ dst, int n, const int* __restrict__ flag) {
  int i = (blockIdx.x * 256 + threadIdx.x) * 8;
  if (i >= n) return;
  if (flag[0]) {
    f32x4 a = *(const f32x4*)(fsrc + i);
    f32x4 b = *(const f32x4*)(fsrc + i + 4);
    ushort8 o;
    #pragma unroll
    for (int e = 0; e < 4; ++e) { o[e] = f2bf(a[e]); o[e + 4] = f2bf(b[e]); }
    *(ushort8*)(dst + i) = o;
  } else {
    *(ushort8*)(dst + i) = *(const ushort8*)(usrc + i);
  }
}

// weight frag-order transform (one-time):
// dst[((nt*16 + ks)*64 + lane)*8 + e] = W[k = ks*32 + (lane>>4)*8 + e][n = nt*16 + (lane&15)]
// W row-major [K=512][NCOL]. Layout makes each MFMA B-frag a contiguous 1KiB wave load.
__global__ void wfrag_k(const float* __restrict__ fsrc, const u16* __restrict__ usrc,
                        u16* __restrict__ dst, int NCOL, const int* __restrict__ flag) {
  int idx = blockIdx.x * 256 + threadIdx.x;   // one elem each; total = NCOL*512
  int e = idx & 7, lane = (idx >> 3) & 63, ks = (idx >> 9) & 15, nt = idx >> 13;
  int n = nt * 16 + (lane & 15);
  int k = ks * 32 + (lane >> 4) * 8 + e;
  size_t src = (size_t)k * NCOL + n;
  dst[idx] = flag[0] ? f2bf(fsrc[src]) : usrc[src];
}

// per-window frag-order x transform: one block (256 thr) per window.
// xf[blk][((ks*4 + mi)*64 + lane)*8 + e] = x[blk*64 + mi*16+(lane&15)][ks*32+(lane>>4)*8+e]
__global__ __launch_bounds__(256) void cvtfrag_k(
    const float* __restrict__ fsrc, const u16* __restrict__ usrc,
    u16* __restrict__ xf, const int* __restrict__ flag)
{
  __shared__ __attribute__((aligned(16))) u16 xl[64 * XPAD];   // 68.6 KB
  const int t = threadIdx.x;
  const size_t wbase = (size_t)blockIdx.x * (NTOK * DIM);

  if (flag[0]) {
    #pragma unroll
    for (int c = 0; c < 32; ++c) {
      int i = c * 1024 + t * 4;            // elem idx in window (coalesced f32x4 read)
      f32x4 v = *(const f32x4*)(fsrc + wbase + i);
      int tok = i >> 9, k = i & 511;
      u16x4 o;
      #pragma unroll
      for (int e = 0; e < 4; ++e) o[e] = f2bf(v[e]);
      *(u16x4*)&xl[tok * XPAD + k] = o;
    }
  } else {
    #pragma unroll
    for (int c = 0; c < 16; ++c) {
      int i = c * 2048 + t * 8;
      ushort8 v = *(const ushort8*)(usrc + wbase + i);
      int tok = i >> 9, k = i & 511;
      *(ushort8*)&xl[tok * XPAD + k] = v;
    }
  }
  __syncthreads();

  u16* dst = xf + wbase;                    // frag-order, same total size
  #pragma unroll
  for (int j = 0; j < 16; ++j) {
    int idx8 = j * 256 + t;                 // [0,4096): 16B chunk id
    int lane = idx8 & 63, mi = (idx8 >> 6) & 3, ks = idx8 >> 8;
    int tok = mi * 16 + (lane & 15);
    int k = ks * 32 + (lane >> 4) * 8;
    ushort8 v = *(const ushort8*)&xl[tok * XPAD + k];
    *(ushort8*)(dst + (size_t)idx8 * 8) = v;   // coalesced global write
  }
}

// biasc[h][mi][ni][lane][r] = table[h, i1-i2+7, j1-j2+7]
__global__ void bias_expand_k(const float* __restrict__ ftab, const u16* __restrict__ utab,
                              float* __restrict__ biasc, const int* __restrict__ flag) {
  int t = blockIdx.x * 256 + threadIdx.x;   // 65536 total
  int r    = t & 3;
  int lane = (t >> 2) & 63;
  int ni   = (t >> 8) & 3;
  int mi   = (t >> 10) & 3;
  int h    = t >> 12;
  int n = mi * 16 + (lane >> 4) * 4 + r;
  int m = ni * 16 + (lane & 15);
  int i1 = n >> 3, j1 = n & 7, i2 = m >> 3, j2 = m & 7;
  int off = h * 225 + (i1 - i2 + 7) * 15 + (j1 - j2 + 7);
  if (flag[0]) biasc[t] = ftab[off];
  else         biasc[t] = bf2f(utab[off]);
}

// ---------------- fully fused per-window kernel (coalesced frag loads) ----------------
// One block = one 64-token window. 8 waves; round r in {0,1}: wave w owns head h=r*8+w.
// All global A/B fragment loads are contiguous 1KiB per wave (frag-order layouts).
__global__ __launch_bounds__(512, 1) void fused_k(
    const u16* __restrict__ xf,       // [win][16][4][64][8] frag-order bf16 x
    const u16* __restrict__ wqf,      // [96][16][64][8] frag-order wqkv
    const u16* __restrict__ bqc,      // [1536]
    const float* __restrict__ biasc,  // [16][4][4][64][4]
    const u16* __restrict__ wpf,      // [32][16][64][8] frag-order wproj
    const u16* __restrict__ bpc,      // [512]
    const int* __restrict__ flag,
    u16* __restrict__ outU, float* __restrict__ outF)
{
  __shared__ __attribute__((aligned(16))) u16 lds[8][REGION];   // 110,592 B

  const int lane = threadIdx.x & 63;
  const int wave = threadIdx.x >> 6;     // 0..7
  const int lr = lane & 15, quad = lane >> 4;
  const int blk = blockIdx.x;

  u16* ql = &lds[wave][0];
  u16* kl = &lds[wave][2304];
  u16* Pl = &lds[wave][0];       // P[64][72] overwrites q,k
  u16* vt = &lds[wave][4608];    // v^T[32][72]
  u16* Ol = &lds[wave][0];       // O_h[64][QSTR] overwrites P

  const u16* xw = xf + (size_t)blk * (NTOK * DIM) + lane * 8;
  const float SCALE = 0.17677669529663687f;   // 32^-0.5
  const float L2E = 1.44269504088896f;
  const f32x4 zero4 = {0.f, 0.f, 0.f, 0.f};

  // persistent projection accumulators: out[64][wave*64 .. +64]
  f32x4 acc[4][4];
  #pragma unroll
  for (int mi = 0; mi < 4; ++mi)
    #pragma unroll
    for (int ni = 0; ni < 4; ++ni) acc[mi][ni] = zero4;

  for (int r = 0; r < 2; ++r) {
    const int h = r * 8 + wave;

    // ---- qkv GEMM for head h: M=64, N=96 (q|k|v x 2 col-tiles), K=512 ----
    f32x4 aq[4][2], ak[4][2], av[4][2];
    #pragma unroll
    for (int mi = 0; mi < 4; ++mi) {
      aq[mi][0] = zero4; aq[mi][1] = zero4;
      ak[mi][0] = zero4; ak[mi][1] = zero4;
      av[mi][0] = zero4; av[mi][1] = zero4;
    }
    // frag-order weight bases: nt = m*32 + h*2 + j  -> elem offset nt*8192
    const u16* wb = wqf + (size_t)(h * 2) * 8192 + lane * 8;
    #pragma unroll 4
    for (int ks = 0; ks < 16; ++ks) {
      short8 af[4];
      #pragma unroll
      for (int mi = 0; mi < 4; ++mi)
        af[mi] = *(const short8*)(xw + (ks * 4 + mi) * 512);
      short8 b0 = *(const short8*)(wb + ks * 512);                 // q j=0
      short8 b1 = *(const short8*)(wb + 8192 + ks * 512);          // q j=1
      short8 b2 = *(const short8*)(wb + 32 * 8192 + ks * 512);     // k j=0
      short8 b3 = *(const short8*)(wb + 33 * 8192 + ks * 512);     // k j=1
      short8 b4 = *(const short8*)(wb + 64 * 8192 + ks * 512);     // v j=0
      short8 b5 = *(const short8*)(wb + 65 * 8192 + ks * 512);     // v j=1
      #pragma unroll
      for (int mi = 0; mi < 4; ++mi) {
        aq[mi][0] = __builtin_amdgcn_mfma_f32_16x16x32_bf16(af[mi], b0, aq[mi][0], 0, 0, 0);
        aq[mi][1] = __builtin_amdgcn_mfma_f32_16x16x32_bf16(af[mi], b1, aq[mi][1], 0, 0, 0);
        ak[mi][0] = __builtin_amdgcn_mfma_f32_16x16x32_bf16(af[mi], b2, ak[mi][0], 0, 0, 0);
        ak[mi][1] = __builtin_amdgcn_mfma_f32_16x16x32_bf16(af[mi], b3, ak[mi][1], 0, 0, 0);
        av[mi][0] = __builtin_amdgcn_mfma_f32_16x16x32_bf16(af[mi], b4, av[mi][0], 0, 0, 0);
        av[mi][1] = __builtin_amdgcn_mfma_f32_16x16x32_bf16(af[mi], b5, av[mi][1], 0, 0, 0);
      }
    }

    // bias + (q: scale) -> LDS. C-layout: tok = mi*16+quad*4+e, d = j*16+lr
    #pragma unroll
    for (int j = 0; j < 2; ++j) {
      float bq = bf2f(bqc[h * 32 + j * 16 + lr]);
      float bk = bf2f(bqc[512 + h * 32 + j * 16 + lr]);
      float bv = bf2f(bqc[1024 + h * 32 + j * 16 + lr]);
      #pragma unroll
      for (int mi = 0; mi < 4; ++mi)
        #pragma unroll
        for (int e = 0; e < 4; ++e) {
          int tok = mi * 16 + quad * 4 + e;
          int d = j * 16 + lr;
          ql[tok * QSTR + d] = f2bf((aq[mi][j][e] + bq) * SCALE);
          kl[tok * QSTR + d] = f2bf(ak[mi][j][e] + bk);
          vt[d * 72 + tok]   = f2bf(av[mi][j][e] + bv);
        }
    }
    // same-wave LDS RAW below: compiler inserts lgkmcnt waits

    // ---- S = q @ k^T (4x4 tiles, K=32) ----
    f32x4 s[4][4];
    {
      short8 afq[4], bfk[4];
      #pragma unroll
      for (int mi = 0; mi < 4; ++mi)
        afq[mi] = *(const short8*)&ql[(mi * 16 + lr) * QSTR + quad * 8];
      #pragma unroll
      for (int ni = 0; ni < 4; ++ni)
        bfk[ni] = *(const short8*)&kl[(ni * 16 + lr) * QSTR + quad * 8];
      #pragma unroll
      for (int mi = 0; mi < 4; ++mi)
        #pragma unroll
        for (int ni = 0; ni < 4; ++ni)
          s[mi][ni] = __builtin_amdgcn_mfma_f32_16x16x32_bf16(afq[mi], bfk[ni], zero4, 0, 0, 0);
    }

    // rel-pos bias (pre-expanded C-layout)
    #pragma unroll
    for (int mi = 0; mi < 4; ++mi)
      #pragma unroll
      for (int ni = 0; ni < 4; ++ni) {
        f32x4 bb = *(const f32x4*)&biasc[((((h * 4 + mi) * 4 + ni) * 64) + lane) * 4];
        s[mi][ni] = s[mi][ni] + bb;
      }

    // row max (masks 1..8 stay within the quad's 16-lane col group)
    f32x4 mx[4];
    #pragma unroll
    for (int mi = 0; mi < 4; ++mi) {
      mx[mi] = max44(max44(s[mi][0], s[mi][1]), max44(s[mi][2], s[mi][3]));
      #pragma unroll
      for (int m = 1; m <= 8; m <<= 1) mx[mi] = max44(mx[mi], shfl_xor4(mx[mi], m));
    }
    // p = exp(s - mx), row sum
    f32x4 sum[4];
    #pragma unroll
    for (int mi = 0; mi < 4; ++mi) {
      #pragma unroll
      for (int ni = 0; ni < 4; ++ni)
        #pragma unroll
        for (int e = 0; e < 4; ++e)
          s[mi][ni][e] = exp2f((s[mi][ni][e] - mx[mi][e]) * L2E);
      sum[mi] = s[mi][0] + s[mi][1] + s[mi][2] + s[mi][3];
      #pragma unroll
      for (int m = 1; m <= 8; m <<= 1) sum[mi] = sum[mi] + shfl_xor4(sum[mi], m);
    }

    // P (unnormalized) -> bf16 -> LDS, stride 72
    #pragma unroll
    for (int mi = 0; mi < 4; ++mi)
      #pragma unroll
      for (int ni = 0; ni < 4; ++ni)
        #pragma unroll
        for (int e = 0; e < 4; ++e) {
          int n = mi * 16 + quad * 4 + e;
          int col = ni * 16 + lr;
          Pl[n * 72 + col] = f2bf(s[mi][ni][e]);
        }

    // O = P @ v : M=64, N=32, K=64 (2 k-steps)
    f32x4 o[4][2];
    #pragma unroll
    for (int mi = 0; mi < 4; ++mi) { o[mi][0] = zero4; o[mi][1] = zero4; }
    #pragma unroll
    for (int ks = 0; ks < 2; ++ks) {
      short8 pf[4], vf[2];
      #pragma unroll
      for (int mi = 0; mi < 4; ++mi)
        pf[mi] = *(const short8*)&Pl[(mi * 16 + lr) * 72 + ks * 32 + quad * 8];
      #pragma unroll
      for (int ni = 0; ni < 2; ++ni)
        vf[ni] = *(const short8*)&vt[(ni * 16 + lr) * 72 + ks * 32 + quad * 8];
      #pragma unroll
      for (int mi = 0; mi < 4; ++mi)
        #pragma unroll
        for (int ni = 0; ni < 2; ++ni)
          o[mi][ni] = __builtin_amdgcn_mfma_f32_16x16x32_bf16(pf[mi], vf[ni], o[mi][ni], 0, 0, 0);
    }

    // normalize, O_h -> LDS as A-matrix [tok][d], stride QSTR
    f32x4 rs[4];
    #pragma unroll
    for (int mi = 0; mi < 4; ++mi)
      #pragma unroll
      for (int e = 0; e < 4; ++e) rs[mi][e] = __builtin_amdgcn_rcpf(sum[mi][e]);
    #pragma unroll
    for (int mi = 0; mi < 4; ++mi)
      #pragma unroll
      for (int ni = 0; ni < 2; ++ni)
        #pragma unroll
        for (int e = 0; e < 4; ++e) {
          int tok = mi * 16 + quad * 4 + e;
          int d = ni * 16 + lr;
          Ol[tok * QSTR + d] = f2bf(o[mi][ni][e] * rs[mi][e]);
        }

    __syncthreads();   // all O_h visible

    // ---- proj accumulate: out[:, wave*64..+64] += O_h2 @ Wproj[h2*32.., :] ----
    // B-frag: wpf elem offset ((wave*4+ni)*16 + h2)*512 + lane*8  (contiguous 1KiB/wave)
    const u16* wpb = wpf + (size_t)(wave * 4) * 8192 + lane * 8;
    #pragma unroll 2
    for (int w2 = 0; w2 < 8; ++w2) {
      const u16* Ow = &lds[w2][0];
      const int h2 = r * 8 + w2;
      short8 afO[4], bfW[4];
      #pragma unroll
      for (int mi = 0; mi < 4; ++mi)
        afO[mi] = *(const short8*)&Ow[(mi * 16 + lr) * QSTR + quad * 8];
      #pragma unroll
      for (int ni = 0; ni < 4; ++ni)
        bfW[ni] = *(const short8*)(wpb + ni * 8192 + h2 * 512);
      #pragma unroll
      for (int mi = 0; mi < 4; ++mi)
        #pragma unroll
        for (int ni = 0; ni < 4; ++ni)
          acc[mi][ni] = __builtin_amdgcn_mfma_f32_16x16x32_bf16(afO[mi], bfW[ni], acc[mi][ni], 0, 0, 0);
    }
    __syncthreads();   // O regions reusable next round
  }

  // ---- epilogue: out = acc + b_proj ----
  const int f32o = flag[0];
  if (f32o) {
    // LDS bounce in two 32-row passes for coalesced float4 global writes
    float* lf = (float*)&lds[0][0];   // 32*512*4 = 64 KB of the 110 KB
    #pragma unroll
    for (int pass = 0; pass < 2; ++pass) {
      __syncthreads();
      #pragma unroll
      for (int mi2 = 0; mi2 < 2; ++mi2) {
        int mi = pass * 2 + mi2;
        #pragma unroll
        for (int ni = 0; ni < 4; ++ni) {
          int col = wave * 64 + ni * 16 + lr;
          float bv = bf2f(bpc[col]);
          #pragma unroll
          for (int e = 0; e < 4; ++e) {
            int row = mi2 * 16 + quad * 4 + e;    // within pass
            lf[row * 512 + col] = acc[mi][ni][e] + bv;
          }
        }
      }
      __syncthreads();
      const size_t rowbase = (size_t)(blk * NTOK + pass * 32) * DIM;
      #pragma unroll
      for (int c = 0; c < 8; ++c) {
        int i = c * 2048 + threadIdx.x * 4;       // f32 idx in [0,16384)
        *(f32x4*)(outF + rowbase + i) = *(const f32x4*)(lf + i);
      }
    }
  } else {
    #pragma unroll
    for (int ni = 0; ni < 4; ++ni) {
      int col = wave * 64 + ni * 16 + lr;
      float bv = bf2f(bpc[col]);
      #pragma unroll
      for (int mi = 0; mi < 4; ++mi) {
        size_t rowb = (size_t)(blk * NTOK + mi * 16 + quad * 4);
        #pragma unroll
        for (int e = 0; e < 4; ++e)
          outU[(rowb + e) * (size_t)DIM + col] = f2bf(acc[mi][ni][e] + bv);
      }
    }
  }
}

// ---------------- launch ----------------

extern "C" void kernel_launch(void* const* d_in, const int* in_sizes, int n_in,
                              void* d_out, int out_size, void* d_ws, size_t ws_size,
                              hipStream_t stream)
{
  (void)in_sizes; (void)n_in; (void)out_size;

  const void* x      = d_in[0];   // [2048*64][512]
  const void* w_qkv  = d_in[1];   // [512][1536]
  const void* b_qkv  = d_in[2];   // [1536]
  const void* table  = d_in[3];   // [16][15][15]
  const void* w_proj = d_in[4];   // [512][512]
  const void* b_proj = d_in[5];   // [512]

  char* ws = (char*)d_ws;
  size_t off = 0;
  auto alloc = [&](size_t bytes) -> char* {
    char* p = ws + off; off += (bytes + 255) & ~(size_t)255; return p;
  };
  u16*   wqf    = (u16*)alloc(1572864);   // frag-order wqkv
  u16*   wpf    = (u16*)alloc(524288);    // frag-order wproj
  float* biasc  = (float*)alloc(262144);
  u16*   bqc    = (u16*)alloc(3072);
  u16*   bpc    = (u16*)alloc(1024);
  int*   flag   = (int*)alloc(256);
  size_t fixed  = off;

  int win = 2048;                        // windows per chunk
  while (win > 2 && fixed + (size_t)win * 65536 > ws_size) win >>= 1;
  const int mc = win * 64;               // rows per chunk
  u16* xfC = (u16*)alloc((size_t)mc * 512 * 2);   // frag-order x chunk

  detect_k<<<dim3(1), dim3(64), 0, stream>>>((const u16*)w_qkv, flag);
  wfrag_k<<<dim3(3072), dim3(256), 0, stream>>>((const float*)w_qkv, (const u16*)w_qkv, wqf, 1536, flag);
  wfrag_k<<<dim3(1024), dim3(256), 0, stream>>>((const float*)w_proj, (const u16*)w_proj, wpf, 512, flag);
  bias_expand_k<<<dim3(256), dim3(256), 0, stream>>>((const float*)table, (const u16*)table, biasc, flag);
  cvt8_k<<<dim3(1), dim3(256), 0, stream>>>((const float*)b_qkv, (const u16*)b_qkv, bqc, 1536, flag);
  cvt8_k<<<dim3(1), dim3(256), 0, stream>>>((const float*)b_proj, (const u16*)b_proj, bpc, 512, flag);

  const int nchunk = 2048 / win;
  for (int c = 0; c < nchunk; ++c) {
    size_t base = (size_t)c * mc * 512;   // element offset into x / out

    cvtfrag_k<<<dim3(win), dim3(256), 0, stream>>>(
        (const float*)x + base, (const u16*)x + base, xfC, flag);

    fused_k<<<dim3(win), dim3(512), 0, stream>>>(
        xfC, wqf, bqc, biasc, wpf, bpc, flag,
        (u16*)d_out + base, (float*)d_out + base);
  }
}